// Round 9
// baseline (882.604 us; speedup 1.0000x reference)
//
#include <hip/hip_runtime.h>
#include <hip/hip_bf16.h>
#include <hip/hip_cooperative_groups.h>

namespace cg = cooperative_groups;

#define NN 50000
#define EE 800000
#define KTOP 25000
#define EPSF 1e-5
#define NB 65536            // rank buckets
#define KSHIFT 16           // key >> KSHIFT = bucket
#define TG 768              // cooperative tail grid

// ---------------------------------------------------------------------------
// GEMM1: Y[M,128] = A[M,128] @ W[128,128] + bias, fused per-block BN partials.
// W staged in 32-row chunks -> 34 KiB LDS -> 4 blocks/CU (was 80 KiB -> 2).
// ---------------------------------------------------------------------------
__global__ __launch_bounds__(256, 4) void gemm_bn_stats(const float* __restrict__ A,
                                                        const float* __restrict__ W,
                                                        const float* __restrict__ bias,
                                                        float* __restrict__ Y,
                                                        double* __restrict__ part, int M) {
    __shared__ float Bsc[32][132];   // W chunk [k within chunk][n]
    __shared__ float As[32][132];    // A chunk transposed [k][row]
    int t = threadIdx.x;
    int bm = blockIdx.x * 128;

    const float4* W4 = (const float4*)W;

    float acc[8][8];
#pragma unroll
    for (int i = 0; i < 8; i++)
#pragma unroll
        for (int j = 0; j < 8; j++) acc[i][j] = 0.f;

    int ty = t >> 4;   // 0..15 row group (8 rows each)
    int tx = t & 15;   // 0..15 col group (cols tx*4 and 64+tx*4)

    for (int kc = 0; kc < 4; kc++) {
        __syncthreads();
        // stage W chunk: rows kc*32..+32
#pragma unroll
        for (int i = 0; i < 4; i++) {
            int f4 = t + i * 256;          // 0..1023
            int r = f4 >> 5, c = f4 & 31;
            float4 wv = W4[(kc * 32 + r) * 32 + c];
            *(float4*)&Bsc[r][c * 4] = wv;
        }
        // stage A chunk transposed
#pragma unroll
        for (int i = 0; i < 4; i++) {
            int f4 = t + i * 256;
            int r = f4 >> 3, k4 = f4 & 7;
            int row = bm + r;
            float4 v = make_float4(0.f, 0.f, 0.f, 0.f);
            if (row < M) v = *(const float4*)&A[(size_t)row * 128 + kc * 32 + k4 * 4];
            As[k4 * 4 + 0][r] = v.x;
            As[k4 * 4 + 1][r] = v.y;
            As[k4 * 4 + 2][r] = v.z;
            As[k4 * 4 + 3][r] = v.w;
        }
        __syncthreads();
#pragma unroll
        for (int kk = 0; kk < 32; kk++) {
            float4 a0 = *(float4*)&As[kk][ty * 8];
            float4 a1 = *(float4*)&As[kk][ty * 8 + 4];
            float4 b0 = *(float4*)&Bsc[kk][tx * 4];
            float4 b1 = *(float4*)&Bsc[kk][64 + tx * 4];
            float av[8] = {a0.x, a0.y, a0.z, a0.w, a1.x, a1.y, a1.z, a1.w};
            float bv[8] = {b0.x, b0.y, b0.z, b0.w, b1.x, b1.y, b1.z, b1.w};
#pragma unroll
            for (int i = 0; i < 8; i++)
#pragma unroll
                for (int j = 0; j < 8; j++) acc[i][j] += av[i] * bv[j];
        }
    }

    float4 bb0 = *(const float4*)&bias[tx * 4];
    float4 bb1 = *(const float4*)&bias[64 + tx * 4];
    float s[8], s2[8];
#pragma unroll
    for (int j = 0; j < 8; j++) { s[j] = 0.f; s2[j] = 0.f; }
#pragma unroll
    for (int i = 0; i < 8; i++) {
        int row = bm + ty * 8 + i;
        if (row < M) {
            float4 y0, y1;
            y0.x = acc[i][0] + bb0.x; y0.y = acc[i][1] + bb0.y;
            y0.z = acc[i][2] + bb0.z; y0.w = acc[i][3] + bb0.w;
            y1.x = acc[i][4] + bb1.x; y1.y = acc[i][5] + bb1.y;
            y1.z = acc[i][6] + bb1.z; y1.w = acc[i][7] + bb1.w;
            *(float4*)&Y[(size_t)row * 128 + tx * 4] = y0;
            *(float4*)&Y[(size_t)row * 128 + 64 + tx * 4] = y1;
            s[0] += y0.x; s2[0] += y0.x * y0.x;
            s[1] += y0.y; s2[1] += y0.y * y0.y;
            s[2] += y0.z; s2[2] += y0.z * y0.z;
            s[3] += y0.w; s2[3] += y0.w * y0.w;
            s[4] += y1.x; s2[4] += y1.x * y1.x;
            s[5] += y1.y; s2[5] += y1.y * y1.y;
            s[6] += y1.z; s2[6] += y1.z * y1.z;
            s[7] += y1.w; s2[7] += y1.w * y1.w;
        }
    }
    __syncthreads();                       // As no longer needed
    float2* Sred = (float2*)As;            // [16][128] float2 = 16 KiB, fits
#pragma unroll
    for (int j = 0; j < 8; j++) {
        int col = (j < 4) ? (tx * 4 + j) : (64 + tx * 4 + j - 4);
        Sred[ty * 128 + col] = make_float2(s[j], s2[j]);
    }
    __syncthreads();
    if (t < 128) {
        double S = 0.0, S2 = 0.0;
#pragma unroll
        for (int r = 0; r < 16; r++) {
            float2 v = Sred[r * 128 + t];
            S += (double)v.x;
            S2 += (double)v.y;
        }
        part[((size_t)blockIdx.x * 128 + t) * 2 + 0] = S;
        part[((size_t)blockIdx.x * 128 + t) * 2 + 1] = S2;
    }
}

// ---------------------------------------------------------------------------
// GEMM2: HWs[M,128] = dinv[row] * ( relu(bn1(Yin)) @ W ). Chunked W staging.
// ---------------------------------------------------------------------------
__global__ __launch_bounds__(256, 4) void gemm_bn_apply(const float* __restrict__ Yin,
                                                        const float* __restrict__ W,
                                                        const float* __restrict__ sc,
                                                        const float* __restrict__ sh,
                                                        const float* __restrict__ dinv,
                                                        float* __restrict__ HWs, int M) {
    __shared__ float Bsc[32][132];
    __shared__ float As[32][132];
    int t = threadIdx.x;
    int bm = blockIdx.x * 128;

    const float4* W4 = (const float4*)W;

    float acc[8][8];
#pragma unroll
    for (int i = 0; i < 8; i++)
#pragma unroll
        for (int j = 0; j < 8; j++) acc[i][j] = 0.f;

    int ty = t >> 4;
    int tx = t & 15;

    for (int kc = 0; kc < 4; kc++) {
        __syncthreads();
#pragma unroll
        for (int i = 0; i < 4; i++) {
            int f4 = t + i * 256;
            int r = f4 >> 5, c = f4 & 31;
            float4 wv = W4[(kc * 32 + r) * 32 + c];
            *(float4*)&Bsc[r][c * 4] = wv;
        }
#pragma unroll
        for (int i = 0; i < 4; i++) {
            int f4 = t + i * 256;
            int r = f4 >> 3, k4 = f4 & 7;
            int row = bm + r;
            int col = kc * 32 + k4 * 4;
            float4 v = make_float4(0.f, 0.f, 0.f, 0.f);
            if (row < M) {
                float4 y = *(const float4*)&Yin[(size_t)row * 128 + col];
                float4 scv = *(const float4*)&sc[col];
                float4 shv = *(const float4*)&sh[col];
                v.x = fmaxf(y.x * scv.x + shv.x, 0.f);
                v.y = fmaxf(y.y * scv.y + shv.y, 0.f);
                v.z = fmaxf(y.z * scv.z + shv.z, 0.f);
                v.w = fmaxf(y.w * scv.w + shv.w, 0.f);
            }
            As[k4 * 4 + 0][r] = v.x;
            As[k4 * 4 + 1][r] = v.y;
            As[k4 * 4 + 2][r] = v.z;
            As[k4 * 4 + 3][r] = v.w;
        }
        __syncthreads();
#pragma unroll
        for (int kk = 0; kk < 32; kk++) {
            float4 a0 = *(float4*)&As[kk][ty * 8];
            float4 a1 = *(float4*)&As[kk][ty * 8 + 4];
            float4 b0 = *(float4*)&Bsc[kk][tx * 4];
            float4 b1 = *(float4*)&Bsc[kk][64 + tx * 4];
            float av[8] = {a0.x, a0.y, a0.z, a0.w, a1.x, a1.y, a1.z, a1.w};
            float bv[8] = {b0.x, b0.y, b0.z, b0.w, b1.x, b1.y, b1.z, b1.w};
#pragma unroll
            for (int i = 0; i < 8; i++)
#pragma unroll
                for (int j = 0; j < 8; j++) acc[i][j] += av[i] * bv[j];
        }
    }
#pragma unroll
    for (int i = 0; i < 8; i++) {
        int row = bm + ty * 8 + i;
        if (row < M) {
            float di = dinv[row];
            float4 o0, o1;
            o0.x = acc[i][0] * di; o0.y = acc[i][1] * di;
            o0.z = acc[i][2] * di; o0.w = acc[i][3] * di;
            o1.x = acc[i][4] * di; o1.y = acc[i][5] * di;
            o1.z = acc[i][6] * di; o1.w = acc[i][7] * di;
            *(float4*)&HWs[(size_t)row * 128 + tx * 4] = o0;
            *(float4*)&HWs[(size_t)row * 128 + 64 + tx * 4] = o1;
        }
    }
}

// ---------------------------------------------------------------------------
// BN finalize (f64 partials, BN1) / (f32 partials, BN2)
// ---------------------------------------------------------------------------
__global__ __launch_bounds__(256) void bn_finalize(const double* __restrict__ part, int nb,
                                                   const float* __restrict__ g,
                                                   const float* __restrict__ beta,
                                                   float* __restrict__ scale,
                                                   float* __restrict__ shift, int M) {
    int c = blockIdx.x;
    int t = threadIdx.x;
    double s = 0.0, s2 = 0.0;
    for (int b = t; b < nb; b += 256) {
        s += part[((size_t)b * 128 + c) * 2 + 0];
        s2 += part[((size_t)b * 128 + c) * 2 + 1];
    }
    __shared__ double sd[256], sd2[256];
    sd[t] = s;
    sd2[t] = s2;
    __syncthreads();
#pragma unroll
    for (int o = 128; o > 0; o >>= 1) {
        if (t < o) {
            sd[t] += sd[t + o];
            sd2[t] += sd2[t + o];
        }
        __syncthreads();
    }
    if (t == 0) {
        double S = sd[0], S2 = sd2[0];
        double mu = S / (double)M;
        double var = S2 / (double)M - mu * mu;
        double inv = 1.0 / sqrt(var + (double)EPSF);
        scale[c] = (float)((double)g[c] * inv);
        shift[c] = (float)((double)beta[c] - mu * (double)g[c] * inv);
    }
}

__global__ __launch_bounds__(256) void bn_finalize2(const float2* __restrict__ part, int nb,
                                                    const float* __restrict__ g,
                                                    const float* __restrict__ beta,
                                                    float* __restrict__ scale,
                                                    float* __restrict__ shift, int M) {
    int c = blockIdx.x;
    int t = threadIdx.x;
    double s = 0.0, s2 = 0.0;
    for (int b = t; b < nb; b += 256) {
        float2 v = part[(size_t)b * 128 + c];
        s += (double)v.x;
        s2 += (double)v.y;
    }
    __shared__ double sd[256], sd2[256];
    sd[t] = s;
    sd2[t] = s2;
    __syncthreads();
#pragma unroll
    for (int o = 128; o > 0; o >>= 1) {
        if (t < o) {
            sd[t] += sd[t + o];
            sd2[t] += sd2[t + o];
        }
        __syncthreads();
    }
    if (t == 0) {
        double S = sd[0], S2 = sd2[0];
        double mu = S / (double)M;
        double var = S2 / (double)M - mu * mu;
        double inv = 1.0 / sqrt(var + (double)EPSF);
        scale[c] = (float)((double)g[c] * inv);
        shift[c] = (float)((double)beta[c] - mu * (double)g[c] * inv);
    }
}

// ---------------------------------------------------------------------------
// Graph: degree count (also zeroes rank-bucket arrays), CSR build (folded scan)
// ---------------------------------------------------------------------------
__global__ __launch_bounds__(256) void count_deg(const int* __restrict__ col,
                                                 int* __restrict__ cnt,
                                                 int* __restrict__ zbase, int zn, int E) {
    int e = blockIdx.x * 256 + threadIdx.x;
    if (e < zn) zbase[e] = 0;            // zero bcnt+bcur (used much later)
    if (e < E) atomicAdd(&cnt[col[e]], 1);
}

__global__ __launch_bounds__(256) void fill_csr(const int* __restrict__ row,
                                                const int* __restrict__ col,
                                                const int* __restrict__ off,
                                                const int* __restrict__ bsum,
                                                int* __restrict__ cur,
                                                int* __restrict__ csr, int E) {
    int e = blockIdx.x * 256 + threadIdx.x;
    if (e < E) {
        int c = col[e];
        int p = atomicAdd(&cur[c], 1);
        csr[off[c] + bsum[c >> 10] + p] = row[e];
    }
}

// ---------------------------------------------------------------------------
// Scan for CSR offsets (phase1 + tiny phase2; consumers fold bsum on the fly)
// ---------------------------------------------------------------------------
__device__ __forceinline__ int waveInclScan(int v, int lane) {
#pragma unroll
    for (int o = 1; o < 64; o <<= 1) {
        int u = __shfl_up(v, o, 64);
        if (lane >= o) v += u;
    }
    return v;
}

__global__ __launch_bounds__(1024) void scan_phase1(const int* __restrict__ in,
                                                    int* __restrict__ out,
                                                    int* __restrict__ bsum,
                                                    float* __restrict__ dinv, int n) {
    int t = threadIdx.x;
    int g = blockIdx.x * 1024 + t;
    int lane = t & 63, wid = t >> 6;
    int v = (g < n) ? in[g] : 0;
    if (dinv && g < n) dinv[g] = (float)(1.0 / sqrt((double)(v + 1)));
    int incl = waveInclScan(v, lane);
    __shared__ int ws[16];
    if (lane == 63) ws[wid] = incl;
    __syncthreads();
    if (t < 16) {
        int x = ws[t];
#pragma unroll
        for (int o = 1; o < 16; o <<= 1) {
            int u = __shfl_up(x, o, 64);
            if (t >= o) x += u;
        }
        ws[t] = x;
    }
    __syncthreads();
    int pre = (wid > 0) ? ws[wid - 1] : 0;
    if (g < n) out[g] = pre + incl - v;
    if (t == 1023) bsum[blockIdx.x] = ws[15];
}

__global__ __launch_bounds__(1024) void scan_phase2(int* __restrict__ bsum, int B) {
    int t = threadIdx.x;
    int lane = t & 63, wid = t >> 6;
    int v = (t < B) ? bsum[t] : 0;
    int incl = waveInclScan(v, lane);
    __shared__ int ws[16];
    if (lane == 63) ws[wid] = incl;
    __syncthreads();
    if (t < 16) {
        int x = ws[t];
#pragma unroll
        for (int o = 1; o < 16; o <<= 1) {
            int u = __shfl_up(x, o, 64);
            if (t >= o) x += u;
        }
        ws[t] = x;
    }
    __syncthreads();
    int pre = (wid > 0) ? ws[wid - 1] : 0;
    if (t < B) bsum[t] = pre + incl - v;   // exclusive block offsets
}

// ---------------------------------------------------------------------------
// GCN aggregation + fused BN2 partials (unchanged from R8 — at random-gather floor)
// ---------------------------------------------------------------------------
__global__ __launch_bounds__(512) void gcn_agg(const float* __restrict__ HWs,
                                               const int* __restrict__ off,
                                               const int* __restrict__ bsum,
                                               const int* __restrict__ csr,
                                               const float* __restrict__ dinv,
                                               const float* __restrict__ gcn_b,
                                               float* __restrict__ OUT,
                                               float2* __restrict__ part32, int M) {
    int t = threadIdx.x;
    int w = t >> 6;            // wave 0..7
    int lane = t & 63;
    int half = lane >> 5;      // 0: even edge, 1: odd edge
    int l32 = lane & 31;       // float4 index within row
    int i = blockIdx.x * 8 + w;

    const float4* H4 = (const float4*)HWs;
    double a0 = 0.0, a1 = 0.0, a2 = 0.0, a3 = 0.0;

    if (i < M) {
        int o0 = off[i] + bsum[i >> 10];
        int o1 = (i + 1 < M) ? (off[i + 1] + bsum[(i + 1) >> 10]) : EE;
        if (half == 0) {   // self-loop term on the even half
            float4 sv = H4[(size_t)i * 32 + l32];
            a0 = sv.x; a1 = sv.y; a2 = sv.z; a3 = sv.w;
        }
        int e = o0;
        for (; e + 4 <= o1; e += 4) {
            int sA = csr[e + half];
            int sB = csr[e + 2 + half];
            float4 vA = H4[(size_t)sA * 32 + l32];
            float4 vB = H4[(size_t)sB * 32 + l32];
            a0 += (double)vA.x + (double)vB.x;
            a1 += (double)vA.y + (double)vB.y;
            a2 += (double)vA.z + (double)vB.z;
            a3 += (double)vA.w + (double)vB.w;
        }
        if (e + 2 <= o1) {
            int sA = csr[e + half];
            float4 vA = H4[(size_t)sA * 32 + l32];
            a0 += (double)vA.x; a1 += (double)vA.y;
            a2 += (double)vA.z; a3 += (double)vA.w;
            e += 2;
        }
        if (e < o1 && half == 0) {
            int sA = csr[e];
            float4 vA = H4[(size_t)sA * 32 + l32];
            a0 += (double)vA.x; a1 += (double)vA.y;
            a2 += (double)vA.z; a3 += (double)vA.w;
        }
    }
    a0 += __shfl_down(a0, 32, 64);
    a1 += __shfl_down(a1, 32, 64);
    a2 += __shfl_down(a2, 32, 64);
    a3 += __shfl_down(a3, 32, 64);

    __shared__ float4 sredS[8][32];
    __shared__ float4 sredQ[8][32];
    if (half == 0) {
        if (i < M) {
            double di = (double)dinv[i];
            float4 gb = ((const float4*)gcn_b)[l32];
            float4 y;
            y.x = (float)(a0 * di) + gb.x;
            y.y = (float)(a1 * di) + gb.y;
            y.z = (float)(a2 * di) + gb.z;
            y.w = (float)(a3 * di) + gb.w;
            ((float4*)OUT)[(size_t)i * 32 + l32] = y;
            sredS[w][l32] = y;
            sredQ[w][l32] = make_float4(y.x * y.x, y.y * y.y, y.z * y.z, y.w * y.w);
        } else {
            sredS[w][l32] = make_float4(0.f, 0.f, 0.f, 0.f);
            sredQ[w][l32] = make_float4(0.f, 0.f, 0.f, 0.f);
        }
    }
    __syncthreads();
    if (t < 128) {
        const float* fS = (const float*)sredS;
        const float* fQ = (const float*)sredQ;
        float S = 0.f, S2 = 0.f;
#pragma unroll
        for (int ww = 0; ww < 8; ww++) {
            S += fS[ww * 128 + t];
            S2 += fQ[ww * 128 + t];
        }
        part32[(size_t)blockIdx.x * 128 + t] = make_float2(S, S2);
    }
}

// ---------------------------------------------------------------------------
// Cooperative tail: score+key+hist -> bucket scan -> bucket fill -> rank+pool
// -> edges. One kernel, grid.sync() between phases. TG blocks x 256 threads.
// ---------------------------------------------------------------------------
__global__ __launch_bounds__(256, 4) void topk_fused(const float* __restrict__ Y2,
                                                     const float* __restrict__ sc,
                                                     const float* __restrict__ sh,
                                                     const float* __restrict__ pw,
                                                     float* __restrict__ score,
                                                     unsigned* __restrict__ key,
                                                     int* __restrict__ bcnt,
                                                     int* __restrict__ bcur,
                                                     int* __restrict__ boff,
                                                     int* __restrict__ gbsum,
                                                     uint2* __restrict__ bmem,
                                                     int* __restrict__ nidx,
                                                     float* __restrict__ out0,
                                                     float* __restrict__ out1,
                                                     float* __restrict__ out2,
                                                     const int* __restrict__ erow,
                                                     const int* __restrict__ ecol,
                                                     int M, int E) {
    cg::grid_group grid = cg::this_grid();
    __shared__ int lrank[256];
    __shared__ float lscore[256];
    __shared__ int ws4[4];

    int t = threadIdx.x;
    int b = blockIdx.x;
    int G = gridDim.x;
    int lane = t & 63;
    int wid = t >> 6;

    // ---- P1: score + key + bucket histogram ----
    {
        float w0 = pw[lane], w1 = pw[lane + 64];
        float sc0 = sc[lane], sh0 = sh[lane];
        float sc1 = sc[lane + 64], sh1 = sh[lane + 64];
        float nv = w0 * w0 + w1 * w1;
#pragma unroll
        for (int o = 32; o >= 1; o >>= 1) nv += __shfl_xor(nv, o, 64);
        float nrm = sqrtf(nv);
        for (int r = b * 4 + wid; r < M; r += G * 4) {
            float a = Y2[(size_t)r * 128 + lane];
            float bb = Y2[(size_t)r * 128 + lane + 64];
            a = fmaxf(a * sc0 + sh0, 0.f);
            bb = fmaxf(bb * sc1 + sh1, 0.f);
            float v = a * w0 + bb * w1;
#pragma unroll
            for (int o = 32; o >= 1; o >>= 1) v += __shfl_xor(v, o, 64);
            if (lane == 0) {
                score[r] = tanhf(v / nrm);
                unsigned u = __float_as_uint(v);
                unsigned k = (u & 0x80000000u) ? ~u : (u | 0x80000000u);
                key[r] = k;
                atomicAdd(&bcnt[k >> KSHIFT], 1);
            }
        }
    }
    grid.sync();

    // ---- P2a: per-64-bucket local scan (one wave per group) ----
    {
        int g0 = b * 4 + wid;              // group of 64 buckets
        if (g0 < (NB >> 6)) {
            int bb = (g0 << 6) + lane;
            int v = bcnt[bb];
            int incl = waveInclScan(v, lane);
            boff[bb] = incl - v;           // local exclusive
            if (lane == 63) gbsum[g0] = incl;
        }
    }
    grid.sync();

    // ---- P2b: block 0 scans gbsum[1024] exclusive ----
    if (b == 0) {
        int v0 = gbsum[t * 4 + 0], v1 = gbsum[t * 4 + 1];
        int v2 = gbsum[t * 4 + 2], v3 = gbsum[t * 4 + 3];
        int s4 = v0 + v1 + v2 + v3;
        int incl = waveInclScan(s4, lane);
        if (lane == 63) ws4[wid] = incl;
        __syncthreads();
        int pre = 0;
#pragma unroll
        for (int q = 0; q < 4; q++)
            if (q < wid) pre += ws4[q];
        int ex = pre + incl - s4;
        gbsum[t * 4 + 0] = ex;
        gbsum[t * 4 + 1] = ex + v0;
        gbsum[t * 4 + 2] = ex + v0 + v1;
        gbsum[t * 4 + 3] = ex + v0 + v1 + v2;
    }
    grid.sync();

    // ---- P2c: add group prefix -> global exclusive boff ----
    {
        int g0 = b * 4 + wid;
        if (g0 < (NB >> 6)) boff[(g0 << 6) + lane] += gbsum[g0];
    }
    grid.sync();

    // ---- P3: bucket fill ----
    for (int i = b * 256 + t; i < M; i += G * 256) {
        unsigned k = key[i];
        int bb = k >> KSHIFT;
        int p = atomicAdd(&bcur[bb], 1);
        bmem[boff[bb] + p] = make_uint2(k, (unsigned)i);
    }
    grid.sync();

    // ---- P4: rank + pool write (stripes of 256 nodes) ----
    {
        int nst = (M + 255) / 256;
        for (int s = b; s < nst; s += G) {
            int base = s * 256;
            int i = base + t;
            int r = 0x7fffffff;
            if (i < M) {
                unsigned ki = key[i];
                int bb = ki >> KSHIFT;
                int p0 = boff[bb];
                int p1 = (bb + 1 < NB) ? boff[bb + 1] : M;
                r = M - p1;
                for (int p = p0; p < p1; p++) {
                    uint2 kj = bmem[p];
                    if (kj.x > ki || (kj.x == ki && (int)kj.y < i)) r++;
                }
                nidx[i] = (r < KTOP) ? r : -1;
                lscore[t] = score[i];
            }
            lrank[t] = r;
            __syncthreads();

            int sub = t >> 5;
            int c4 = t & 31;
            float4 scv = *(const float4*)&sc[c4 * 4];
            float4 shv = *(const float4*)&sh[c4 * 4];
            for (int n0 = 0; n0 < 256; n0 += 8) {
                int li = n0 + sub;
                int node = base + li;
                if (node < M) {
                    int rr = lrank[li];
                    if (rr < KTOP) {
                        float sv = lscore[li];
                        float4 y = *(const float4*)&Y2[(size_t)node * 128 + c4 * 4];
                        float4 o;
                        o.x = fmaxf(y.x * scv.x + shv.x, 0.f) * sv;
                        o.y = fmaxf(y.y * scv.y + shv.y, 0.f) * sv;
                        o.z = fmaxf(y.z * scv.z + shv.z, 0.f) * sv;
                        o.w = fmaxf(y.w * scv.w + shv.w, 0.f) * sv;
                        *(float4*)&out0[(size_t)rr * 128 + c4 * 4] = o;
                        if (c4 == 0) out2[rr] = 0.0f;   // batch_new
                    }
                }
            }
            __syncthreads();
        }
    }
    grid.sync();

    // ---- P5: edges ----
    for (int e = b * 256 + t; e < E; e += G * 256) {
        int a = nidx[erow[e]];
        int bb = nidx[ecol[e]];
        bool keep = (a >= 0) && (bb >= 0);
        out1[e] = keep ? (float)a : -1.0f;
        out1[E + e] = keep ? (float)bb : -1.0f;
    }
}

// ---------------------------------------------------------------------------
extern "C" void kernel_launch(void* const* d_in, const int* in_sizes, int n_in,
                              void* d_out, int out_size, void* d_ws, size_t ws_size,
                              hipStream_t stream) {
    const float* x = (const float*)d_in[0];
    const int* ei = (const int*)d_in[1];
    const float* lin_w = (const float*)d_in[3];
    const float* lin_b = (const float*)d_in[4];
    const float* bn1_g = (const float*)d_in[5];
    const float* bn1_b = (const float*)d_in[6];
    const float* gcn_w = (const float*)d_in[7];
    const float* gcn_b = (const float*)d_in[8];
    const float* bn2_g = (const float*)d_in[9];
    const float* bn2_b = (const float*)d_in[10];
    const float* pool_w = (const float*)d_in[11];

    const int* e_row = ei;        // edge_index[0]
    const int* e_col = ei + EE;   // edge_index[1]

    char* ws = (char*)d_ws;
    size_t off_b = 0;
    auto alloc = [&](size_t bytes) -> void* {
        void* p = ws + off_b;
        off_b = (off_b + bytes + 255) & ~(size_t)255;
        return p;
    };
    float* y = (float*)alloc((size_t)NN * 128 * 4);     // gemm1 out, later gcn out (y2)
    float* hws = (float*)alloc((size_t)NN * 128 * 4);   // dinv-scaled h @ gcn_w
    int* cnt = (int*)alloc(NN * 4);
    int* cur = (int*)alloc(NN * 4);                     // adjacent to cnt (1 memset)
    int* offs = (int*)alloc((NN + 1) * 4);
    float* dinv = (float*)alloc(NN * 4);
    int* csr = (int*)alloc((size_t)EE * 4);
    float* score = (float*)alloc(NN * 4);
    unsigned* key = (unsigned*)alloc(NN * 4);
    int* nidx = (int*)alloc(NN * 4);
    int* bcnt = (int*)alloc((size_t)NB * 4);
    int* bcur = (int*)alloc((size_t)NB * 4);            // adjacent to bcnt
    int* boff = (int*)alloc(((size_t)NB + 1) * 4);
    uint2* bmem = (uint2*)alloc((size_t)NN * 8);
    double* part = (double*)alloc((size_t)400 * 128 * 2 * 8);   // BN1 f64 partials
    float* scale1 = (float*)alloc(128 * 4);
    float* shift1 = (float*)alloc(128 * 4);
    float* scale2 = (float*)alloc(128 * 4);
    float* shift2 = (float*)alloc(128 * 4);
    int* bsumA = (int*)alloc(256 * 4);
    int* gbsum = (int*)alloc(1024 * 4);

    float* out0 = (float*)d_out;                       // x_pool [K,128]
    float* out1 = out0 + (size_t)KTOP * 128;           // ei_new [2,E]
    float* out2 = out1 + (size_t)2 * EE;               // batch_new [K]

    // BN2 f32 partials: reuse x_pool output region as scratch (6.4 MB;
    // fully overwritten by topk_fused P4 at the end).
    float2* part32 = (float2*)out0;
    int gcn_grid = (NN + 7) / 8;                       // 6250
    int gemm_grid = (NN + 127) / 128;                  // 391

    // ---- graph prep ----
    hipMemsetAsync(cnt, 0, (size_t)((char*)cur - (char*)cnt) + NN * 4, stream);
    count_deg<<<(EE + 255) / 256, 256, 0, stream>>>(e_col, cnt, bcnt, 2 * NB, EE);
    {
        int B = (NN + 1023) / 1024;   // 49
        scan_phase1<<<B, 1024, 0, stream>>>(cnt, offs, bsumA, dinv, NN);
        scan_phase2<<<1, 1024, 0, stream>>>(bsumA, B);
    }
    fill_csr<<<(EE + 255) / 256, 256, 0, stream>>>(e_row, e_col, offs, bsumA, cur, csr, EE);

    // ---- MLP: Linear (+ fused BN1 stats) ----
    gemm_bn_stats<<<gemm_grid, 256, 0, stream>>>(x, lin_w, lin_b, y, part, NN);
    bn_finalize<<<128, 256, 0, stream>>>(part, gemm_grid, bn1_g, bn1_b, scale1, shift1, NN);

    // ---- GCN: (BN1+ReLU fused) @ gcn_w, pre-scaled by dinv ----
    gemm_bn_apply<<<gemm_grid, 256, 0, stream>>>(y, gcn_w, scale1, shift1, dinv, hws, NN);
    gcn_agg<<<gcn_grid, 512, 0, stream>>>(hws, offs, bsumA, csr, dinv, gcn_b, y, part32, NN);

    // ---- BN2 finalize (partials fused into gcn_agg) ----
    bn_finalize2<<<128, 256, 0, stream>>>(part32, gcn_grid, bn2_g, bn2_b, scale2, shift2, NN);

    // ---- cooperative fused tail: score -> scan -> fill -> rank+pool -> edges ----
    {
        int Mv = NN, Ev = EE;
        void* args[] = {(void*)&y,     (void*)&scale2, (void*)&shift2, (void*)&pool_w,
                        (void*)&score, (void*)&key,    (void*)&bcnt,   (void*)&bcur,
                        (void*)&boff,  (void*)&gbsum,  (void*)&bmem,   (void*)&nidx,
                        (void*)&out0,  (void*)&out1,   (void*)&out2,
                        (void*)&e_row, (void*)&e_col,  (void*)&Mv,     (void*)&Ev};
        hipLaunchCooperativeKernel((void*)topk_fused, dim3(TG), dim3(256), args, 0, stream);
    }
}

// Round 10
// 403.535 us; speedup vs baseline: 2.1872x; 2.1872x over previous
//
#include <hip/hip_runtime.h>
#include <hip/hip_bf16.h>

#define NN 50000
#define EE 800000
#define KTOP 25000
#define EPSF 1e-5

// ---------------------------------------------------------------------------
// GEMM1: Y[M,128] = A[M,128] @ W[128,128] + bias, fused per-block BN partials.
// W staged in 32-row chunks -> 34 KiB LDS -> 4 blocks/CU.
// ---------------------------------------------------------------------------
__global__ __launch_bounds__(256, 4) void gemm_bn_stats(const float* __restrict__ A,
                                                        const float* __restrict__ W,
                                                        const float* __restrict__ bias,
                                                        float* __restrict__ Y,
                                                        double* __restrict__ part, int M) {
    __shared__ float Bsc[32][132];   // W chunk [k within chunk][n]
    __shared__ float As[32][132];    // A chunk transposed [k][row]
    int t = threadIdx.x;
    int bm = blockIdx.x * 128;

    const float4* W4 = (const float4*)W;

    float acc[8][8];
#pragma unroll
    for (int i = 0; i < 8; i++)
#pragma unroll
        for (int j = 0; j < 8; j++) acc[i][j] = 0.f;

    int ty = t >> 4;   // 0..15 row group (8 rows each)
    int tx = t & 15;   // 0..15 col group (cols tx*4 and 64+tx*4)

    for (int kc = 0; kc < 4; kc++) {
        __syncthreads();
        // stage W chunk: rows kc*32..+32
#pragma unroll
        for (int i = 0; i < 4; i++) {
            int f4 = t + i * 256;          // 0..1023
            int r = f4 >> 5, c = f4 & 31;
            float4 wv = W4[(kc * 32 + r) * 32 + c];
            *(float4*)&Bsc[r][c * 4] = wv;
        }
        // stage A chunk transposed
#pragma unroll
        for (int i = 0; i < 4; i++) {
            int f4 = t + i * 256;
            int r = f4 >> 3, k4 = f4 & 7;
            int row = bm + r;
            float4 v = make_float4(0.f, 0.f, 0.f, 0.f);
            if (row < M) v = *(const float4*)&A[(size_t)row * 128 + kc * 32 + k4 * 4];
            As[k4 * 4 + 0][r] = v.x;
            As[k4 * 4 + 1][r] = v.y;
            As[k4 * 4 + 2][r] = v.z;
            As[k4 * 4 + 3][r] = v.w;
        }
        __syncthreads();
#pragma unroll
        for (int kk = 0; kk < 32; kk++) {
            float4 a0 = *(float4*)&As[kk][ty * 8];
            float4 a1 = *(float4*)&As[kk][ty * 8 + 4];
            float4 b0 = *(float4*)&Bsc[kk][tx * 4];
            float4 b1 = *(float4*)&Bsc[kk][64 + tx * 4];
            float av[8] = {a0.x, a0.y, a0.z, a0.w, a1.x, a1.y, a1.z, a1.w};
            float bv[8] = {b0.x, b0.y, b0.z, b0.w, b1.x, b1.y, b1.z, b1.w};
#pragma unroll
            for (int i = 0; i < 8; i++)
#pragma unroll
                for (int j = 0; j < 8; j++) acc[i][j] += av[i] * bv[j];
        }
    }

    float4 bb0 = *(const float4*)&bias[tx * 4];
    float4 bb1 = *(const float4*)&bias[64 + tx * 4];
    float s[8], s2[8];
#pragma unroll
    for (int j = 0; j < 8; j++) { s[j] = 0.f; s2[j] = 0.f; }
#pragma unroll
    for (int i = 0; i < 8; i++) {
        int row = bm + ty * 8 + i;
        if (row < M) {
            float4 y0, y1;
            y0.x = acc[i][0] + bb0.x; y0.y = acc[i][1] + bb0.y;
            y0.z = acc[i][2] + bb0.z; y0.w = acc[i][3] + bb0.w;
            y1.x = acc[i][4] + bb1.x; y1.y = acc[i][5] + bb1.y;
            y1.z = acc[i][6] + bb1.z; y1.w = acc[i][7] + bb1.w;
            *(float4*)&Y[(size_t)row * 128 + tx * 4] = y0;
            *(float4*)&Y[(size_t)row * 128 + 64 + tx * 4] = y1;
            s[0] += y0.x; s2[0] += y0.x * y0.x;
            s[1] += y0.y; s2[1] += y0.y * y0.y;
            s[2] += y0.z; s2[2] += y0.z * y0.z;
            s[3] += y0.w; s2[3] += y0.w * y0.w;
            s[4] += y1.x; s2[4] += y1.x * y1.x;
            s[5] += y1.y; s2[5] += y1.y * y1.y;
            s[6] += y1.z; s2[6] += y1.z * y1.z;
            s[7] += y1.w; s2[7] += y1.w * y1.w;
        }
    }
    __syncthreads();                       // As no longer needed
    float2* Sred = (float2*)As;            // [16][128] float2 = 16 KiB, fits
#pragma unroll
    for (int j = 0; j < 8; j++) {
        int col = (j < 4) ? (tx * 4 + j) : (64 + tx * 4 + j - 4);
        Sred[ty * 128 + col] = make_float2(s[j], s2[j]);
    }
    __syncthreads();
    if (t < 128) {
        double S = 0.0, S2 = 0.0;
#pragma unroll
        for (int r = 0; r < 16; r++) {
            float2 v = Sred[r * 128 + t];
            S += (double)v.x;
            S2 += (double)v.y;
        }
        part[((size_t)blockIdx.x * 128 + t) * 2 + 0] = S;
        part[((size_t)blockIdx.x * 128 + t) * 2 + 1] = S2;
    }
}

// ---------------------------------------------------------------------------
// GEMM2: HWs[M,128] = dinv[row] * ( relu(bn1(Yin)) @ W ). Chunked W staging.
// ---------------------------------------------------------------------------
__global__ __launch_bounds__(256, 4) void gemm_bn_apply(const float* __restrict__ Yin,
                                                        const float* __restrict__ W,
                                                        const float* __restrict__ sc,
                                                        const float* __restrict__ sh,
                                                        const float* __restrict__ dinv,
                                                        float* __restrict__ HWs, int M) {
    __shared__ float Bsc[32][132];
    __shared__ float As[32][132];
    int t = threadIdx.x;
    int bm = blockIdx.x * 128;

    const float4* W4 = (const float4*)W;

    float acc[8][8];
#pragma unroll
    for (int i = 0; i < 8; i++)
#pragma unroll
        for (int j = 0; j < 8; j++) acc[i][j] = 0.f;

    int ty = t >> 4;
    int tx = t & 15;

    for (int kc = 0; kc < 4; kc++) {
        __syncthreads();
#pragma unroll
        for (int i = 0; i < 4; i++) {
            int f4 = t + i * 256;
            int r = f4 >> 5, c = f4 & 31;
            float4 wv = W4[(kc * 32 + r) * 32 + c];
            *(float4*)&Bsc[r][c * 4] = wv;
        }
#pragma unroll
        for (int i = 0; i < 4; i++) {
            int f4 = t + i * 256;
            int r = f4 >> 3, k4 = f4 & 7;
            int row = bm + r;
            int col = kc * 32 + k4 * 4;
            float4 v = make_float4(0.f, 0.f, 0.f, 0.f);
            if (row < M) {
                float4 y = *(const float4*)&Yin[(size_t)row * 128 + col];
                float4 scv = *(const float4*)&sc[col];
                float4 shv = *(const float4*)&sh[col];
                v.x = fmaxf(y.x * scv.x + shv.x, 0.f);
                v.y = fmaxf(y.y * scv.y + shv.y, 0.f);
                v.z = fmaxf(y.z * scv.z + shv.z, 0.f);
                v.w = fmaxf(y.w * scv.w + shv.w, 0.f);
            }
            As[k4 * 4 + 0][r] = v.x;
            As[k4 * 4 + 1][r] = v.y;
            As[k4 * 4 + 2][r] = v.z;
            As[k4 * 4 + 3][r] = v.w;
        }
        __syncthreads();
#pragma unroll
        for (int kk = 0; kk < 32; kk++) {
            float4 a0 = *(float4*)&As[kk][ty * 8];
            float4 a1 = *(float4*)&As[kk][ty * 8 + 4];
            float4 b0 = *(float4*)&Bsc[kk][tx * 4];
            float4 b1 = *(float4*)&Bsc[kk][64 + tx * 4];
            float av[8] = {a0.x, a0.y, a0.z, a0.w, a1.x, a1.y, a1.z, a1.w};
            float bv[8] = {b0.x, b0.y, b0.z, b0.w, b1.x, b1.y, b1.z, b1.w};
#pragma unroll
            for (int i = 0; i < 8; i++)
#pragma unroll
                for (int j = 0; j < 8; j++) acc[i][j] += av[i] * bv[j];
        }
    }
#pragma unroll
    for (int i = 0; i < 8; i++) {
        int row = bm + ty * 8 + i;
        if (row < M) {
            float di = dinv[row];
            float4 o0, o1;
            o0.x = acc[i][0] * di; o0.y = acc[i][1] * di;
            o0.z = acc[i][2] * di; o0.w = acc[i][3] * di;
            o1.x = acc[i][4] * di; o1.y = acc[i][5] * di;
            o1.z = acc[i][6] * di; o1.w = acc[i][7] * di;
            *(float4*)&HWs[(size_t)row * 128 + tx * 4] = o0;
            *(float4*)&HWs[(size_t)row * 128 + 64 + tx * 4] = o1;
        }
    }
}

// ---------------------------------------------------------------------------
// BN stats (for gcn output): 64 rows/block, unroll-4, f64 partials
// ---------------------------------------------------------------------------
#define BN2_ROWS 64
#define BN2_NB ((NN + BN2_ROWS - 1) / BN2_ROWS)   // 782

__global__ __launch_bounds__(128) void bn_stats(const float* __restrict__ Y,
                                                double* __restrict__ part, int M) {
    int c = threadIdx.x;
    int b = blockIdx.x;
    int r0 = b * BN2_ROWS;
    int r1 = min(M, r0 + BN2_ROWS);
    double s = 0.0, s2 = 0.0;
    int r = r0;
    for (; r + 4 <= r1; r += 4) {
        float v0 = Y[(size_t)r * 128 + c];
        float v1 = Y[(size_t)(r + 1) * 128 + c];
        float v2 = Y[(size_t)(r + 2) * 128 + c];
        float v3 = Y[(size_t)(r + 3) * 128 + c];
        s += (double)v0 + (double)v1 + (double)v2 + (double)v3;
        s2 += (double)v0 * v0 + (double)v1 * v1 + (double)v2 * v2 + (double)v3 * v3;
    }
    for (; r < r1; r++) {
        float v = Y[(size_t)r * 128 + c];
        s += (double)v;
        s2 += (double)v * v;
    }
    part[((size_t)b * 128 + c) * 2 + 0] = s;
    part[((size_t)b * 128 + c) * 2 + 1] = s2;
}

// ---------------------------------------------------------------------------
// BN finalize: parallel — one block per channel, 256 threads, LDS f64 tree.
// ---------------------------------------------------------------------------
__global__ __launch_bounds__(256) void bn_finalize(const double* __restrict__ part, int nb,
                                                   const float* __restrict__ g,
                                                   const float* __restrict__ beta,
                                                   float* __restrict__ scale,
                                                   float* __restrict__ shift, int M) {
    int c = blockIdx.x;
    int t = threadIdx.x;
    double s = 0.0, s2 = 0.0;
    for (int b = t; b < nb; b += 256) {
        s += part[((size_t)b * 128 + c) * 2 + 0];
        s2 += part[((size_t)b * 128 + c) * 2 + 1];
    }
    __shared__ double sd[256], sd2[256];
    sd[t] = s;
    sd2[t] = s2;
    __syncthreads();
#pragma unroll
    for (int o = 128; o > 0; o >>= 1) {
        if (t < o) {
            sd[t] += sd[t + o];
            sd2[t] += sd2[t + o];
        }
        __syncthreads();
    }
    if (t == 0) {
        double S = sd[0], S2 = sd2[0];
        double mu = S / (double)M;
        double var = S2 / (double)M - mu * mu;
        double inv = 1.0 / sqrt(var + (double)EPSF);
        scale[c] = (float)((double)g[c] * inv);
        shift[c] = (float)((double)beta[c] - mu * (double)g[c] * inv);
    }
}

// ---------------------------------------------------------------------------
// Graph: degree count, CSR build
// ---------------------------------------------------------------------------
__global__ __launch_bounds__(256) void count_deg(const int* __restrict__ col,
                                                 int* __restrict__ cnt, int E) {
    int e = blockIdx.x * 256 + threadIdx.x;
    if (e < E) atomicAdd(&cnt[col[e]], 1);
}

__global__ __launch_bounds__(256) void fill_csr(const int* __restrict__ row,
                                                const int* __restrict__ col,
                                                const int* __restrict__ off,
                                                int* __restrict__ cur,
                                                int* __restrict__ csr, int E) {
    int e = blockIdx.x * 256 + threadIdx.x;
    if (e < E) {
        int c = col[e];
        int p = atomicAdd(&cur[c], 1);
        csr[off[c] + p] = row[e];
    }
}

// ---------------------------------------------------------------------------
// Scan (3-phase exclusive scan; phase1 optionally emits dinv = rsqrt(cnt+1))
// ---------------------------------------------------------------------------
__device__ __forceinline__ int waveInclScan(int v, int lane) {
#pragma unroll
    for (int o = 1; o < 64; o <<= 1) {
        int u = __shfl_up(v, o, 64);
        if (lane >= o) v += u;
    }
    return v;
}

__global__ __launch_bounds__(1024) void scan_phase1(const int* __restrict__ in,
                                                    int* __restrict__ out,
                                                    int* __restrict__ bsum,
                                                    float* __restrict__ dinv, int n) {
    int t = threadIdx.x;
    int g = blockIdx.x * 1024 + t;
    int lane = t & 63, wid = t >> 6;
    int v = (g < n) ? in[g] : 0;
    if (dinv && g < n) dinv[g] = (float)(1.0 / sqrt((double)(v + 1)));
    int incl = waveInclScan(v, lane);
    __shared__ int ws[16];
    if (lane == 63) ws[wid] = incl;
    __syncthreads();
    if (t < 16) {
        int x = ws[t];
#pragma unroll
        for (int o = 1; o < 16; o <<= 1) {
            int u = __shfl_up(x, o, 64);
            if (t >= o) x += u;
        }
        ws[t] = x;
    }
    __syncthreads();
    int pre = (wid > 0) ? ws[wid - 1] : 0;
    if (g < n) out[g] = pre + incl - v;
    if (t == 1023) bsum[blockIdx.x] = ws[15];
}

__global__ __launch_bounds__(1024) void scan_phase2(int* __restrict__ bsum, int B,
                                                    int* __restrict__ out, int n) {
    int t = threadIdx.x;
    int lane = t & 63, wid = t >> 6;
    int v = (t < B) ? bsum[t] : 0;
    int incl = waveInclScan(v, lane);
    __shared__ int ws[16];
    if (lane == 63) ws[wid] = incl;
    __syncthreads();
    if (t < 16) {
        int x = ws[t];
#pragma unroll
        for (int o = 1; o < 16; o <<= 1) {
            int u = __shfl_up(x, o, 64);
            if (t >= o) x += u;
        }
        ws[t] = x;
    }
    __syncthreads();
    int pre = (wid > 0) ? ws[wid - 1] : 0;
    int glob_incl = pre + incl;
    if (t < B) bsum[t] = glob_incl - v;   // exclusive
    if (t == B - 1) out[n] = glob_incl;   // grand total
}

__global__ __launch_bounds__(1024) void scan_phase3(int* __restrict__ out,
                                                    const int* __restrict__ bsum, int n) {
    int g = blockIdx.x * 1024 + threadIdx.x;
    if (g < n) out[g] += bsum[blockIdx.x];
}

// ---------------------------------------------------------------------------
// GCN aggregation: one WAVE per node (4 nodes / 256-thr block), float2 per
// lane, unroll-8 gathers for MLP. HWs is pre-scaled by dinv[src].
// OUT[i] = dinv[i]*( sum_src HWs[src] + HWs[i] ) + gcn_b
// ---------------------------------------------------------------------------
__global__ __launch_bounds__(256) void gcn_agg(const float* __restrict__ HWs,
                                               const int* __restrict__ off,
                                               const int* __restrict__ csr,
                                               const float* __restrict__ dinv,
                                               const float* __restrict__ gcn_b,
                                               float* __restrict__ OUT, int M) {
    int lane = threadIdx.x & 63;
    int i = blockIdx.x * 4 + (threadIdx.x >> 6);
    if (i >= M) return;
    const float2* H2 = (const float2*)HWs;
    int o0 = off[i], o1 = off[i + 1];
    float2 hv = H2[(size_t)i * 64 + lane];   // self loop term
    double ax = (double)hv.x, ay = (double)hv.y;
    int e = o0;
    for (; e + 8 <= o1; e += 8) {
        int s0 = csr[e], s1 = csr[e + 1], s2 = csr[e + 2], s3 = csr[e + 3];
        int s4 = csr[e + 4], s5 = csr[e + 5], s6 = csr[e + 6], s7 = csr[e + 7];
        float2 v0 = H2[(size_t)s0 * 64 + lane];
        float2 v1 = H2[(size_t)s1 * 64 + lane];
        float2 v2 = H2[(size_t)s2 * 64 + lane];
        float2 v3 = H2[(size_t)s3 * 64 + lane];
        float2 v4 = H2[(size_t)s4 * 64 + lane];
        float2 v5 = H2[(size_t)s5 * 64 + lane];
        float2 v6 = H2[(size_t)s6 * 64 + lane];
        float2 v7 = H2[(size_t)s7 * 64 + lane];
        ax += ((double)v0.x + (double)v1.x) + ((double)v2.x + (double)v3.x) +
              ((double)v4.x + (double)v5.x) + ((double)v6.x + (double)v7.x);
        ay += ((double)v0.y + (double)v1.y) + ((double)v2.y + (double)v3.y) +
              ((double)v4.y + (double)v5.y) + ((double)v6.y + (double)v7.y);
    }
    for (; e < o1; e++) {
        float2 v = H2[(size_t)csr[e] * 64 + lane];
        ax += (double)v.x;
        ay += (double)v.y;
    }
    double di = (double)dinv[i];
    float2 ob = ((const float2*)gcn_b)[lane];
    float2 o;
    o.x = (float)(ax * di) + ob.x;
    o.y = (float)(ay * di) + ob.y;
    ((float2*)OUT)[(size_t)i * 64 + lane] = o;
}

// ---------------------------------------------------------------------------
// Score (BN2+ReLU on the fly) + orderable key (raw pre-tanh v) + histogram.
// ---------------------------------------------------------------------------
__global__ __launch_bounds__(256) void score_key(const float* __restrict__ Y2,
                                                 const float* __restrict__ sc,
                                                 const float* __restrict__ sh,
                                                 const float* __restrict__ w,
                                                 float* __restrict__ score,
                                                 unsigned* __restrict__ key,
                                                 int* __restrict__ bcnt, int M) {
    int lane = threadIdx.x & 63;
    int wid = threadIdx.x >> 6;
    int gw = blockIdx.x * 4 + wid;
    int nw = gridDim.x * 4;

    float w0 = w[lane], w1 = w[lane + 64];
    float sc0 = sc[lane], sh0 = sh[lane];
    float sc1 = sc[lane + 64], sh1 = sh[lane + 64];

    float nv = w0 * w0 + w1 * w1;
#pragma unroll
    for (int o = 32; o >= 1; o >>= 1) nv += __shfl_xor(nv, o, 64);
    float nrm = sqrtf(nv);

    for (int r = gw; r < M; r += nw) {
        float a = Y2[(size_t)r * 128 + lane];
        float b = Y2[(size_t)r * 128 + lane + 64];
        a = fmaxf(a * sc0 + sh0, 0.f);
        b = fmaxf(b * sc1 + sh1, 0.f);
        float v = a * w0 + b * w1;
#pragma unroll
        for (int o = 32; o >= 1; o >>= 1) v += __shfl_xor(v, o, 64);
        if (lane == 0) {
            score[r] = tanhf(v / nrm);
            unsigned u = __float_as_uint(v);
            unsigned k = (u & 0x80000000u) ? ~u : (u | 0x80000000u);
            key[r] = k;
            atomicAdd(&bcnt[k >> 16], 1);
        }
    }
}

__global__ __launch_bounds__(256) void bucket_fill(const unsigned* __restrict__ key,
                                                   const int* __restrict__ boff,
                                                   int* __restrict__ bcur,
                                                   int* __restrict__ bmem, int M) {
    int i = blockIdx.x * 256 + threadIdx.x;
    if (i < M) {
        int b = key[i] >> 16;
        int p = atomicAdd(&bcur[b], 1);
        bmem[boff[b] + p] = i;
    }
}

__global__ __launch_bounds__(256) void rank_kernel(const unsigned* __restrict__ key,
                                                   const int* __restrict__ boff,
                                                   const int* __restrict__ bmem,
                                                   int* __restrict__ rank,
                                                   int* __restrict__ nidx, int M) {
    int i = blockIdx.x * 256 + threadIdx.x;
    if (i >= M) return;
    unsigned ki = key[i];
    int b = ki >> 16;
    int r = M - boff[b + 1];   // all keys in strictly-greater buckets
    int p0 = boff[b], p1 = boff[b + 1];
    for (int p = p0; p < p1; p++) {
        int j = bmem[p];
        unsigned kj = key[j];
        if (kj > ki || (kj == ki && j < i)) r++;
    }
    rank[i] = r;
    nidx[i] = (r < KTOP) ? r : -1;
}

// ---------------------------------------------------------------------------
// Output writers (d_out: [x_pool K*128 | ei_new 2E | batch_new K], all f32)
// write_pool: 4 nodes per 128-thr block, float4 per thread (32 thr/node)
// ---------------------------------------------------------------------------
__global__ __launch_bounds__(128) void write_pool(const float* __restrict__ Y2,
                                                  const float* __restrict__ sc,
                                                  const float* __restrict__ sh,
                                                  const float* __restrict__ score,
                                                  const int* __restrict__ rank,
                                                  float* __restrict__ out0,
                                                  float* __restrict__ out2, int M) {
    int sub = threadIdx.x >> 5;              // 0..3 node within block
    int c4 = threadIdx.x & 31;               // float4 index 0..31
    int i = blockIdx.x * 4 + sub;
    if (i >= M) return;
    int r = rank[i];
    if (r < KTOP) {
        float s = score[i];
        float4 y = *(const float4*)&Y2[(size_t)i * 128 + c4 * 4];
        float4 scv = *(const float4*)&sc[c4 * 4];
        float4 shv = *(const float4*)&sh[c4 * 4];
        float4 o;
        o.x = fmaxf(y.x * scv.x + shv.x, 0.f) * s;
        o.y = fmaxf(y.y * scv.y + shv.y, 0.f) * s;
        o.z = fmaxf(y.z * scv.z + shv.z, 0.f) * s;
        o.w = fmaxf(y.w * scv.w + shv.w, 0.f) * s;
        *(float4*)&out0[(size_t)r * 128 + c4 * 4] = o;
        if (c4 == 0) out2[r] = 0.0f;   // batch_new (batch is all zeros)
    }
}

__global__ __launch_bounds__(256) void write_edges(const int* __restrict__ row,
                                                   const int* __restrict__ col,
                                                   const int* __restrict__ nidx,
                                                   float* __restrict__ out1, int E) {
    int e = blockIdx.x * 256 + threadIdx.x;
    if (e < E) {
        int a = nidx[row[e]];
        int b = nidx[col[e]];
        bool keep = (a >= 0) && (b >= 0);
        out1[e] = keep ? (float)a : -1.0f;
        out1[E + e] = keep ? (float)b : -1.0f;
    }
}

// ---------------------------------------------------------------------------
extern "C" void kernel_launch(void* const* d_in, const int* in_sizes, int n_in,
                              void* d_out, int out_size, void* d_ws, size_t ws_size,
                              hipStream_t stream) {
    const float* x = (const float*)d_in[0];
    const int* ei = (const int*)d_in[1];
    const float* lin_w = (const float*)d_in[3];
    const float* lin_b = (const float*)d_in[4];
    const float* bn1_g = (const float*)d_in[5];
    const float* bn1_b = (const float*)d_in[6];
    const float* gcn_w = (const float*)d_in[7];
    const float* gcn_b = (const float*)d_in[8];
    const float* bn2_g = (const float*)d_in[9];
    const float* bn2_b = (const float*)d_in[10];
    const float* pool_w = (const float*)d_in[11];

    const int* e_row = ei;        // edge_index[0]
    const int* e_col = ei + EE;   // edge_index[1]

    char* ws = (char*)d_ws;
    size_t off_b = 0;
    auto alloc = [&](size_t bytes) -> void* {
        void* p = ws + off_b;
        off_b = (off_b + bytes + 255) & ~(size_t)255;
        return p;
    };
    float* y = (float*)alloc((size_t)NN * 128 * 4);     // gemm1 out, later gcn out (y2)
    float* hws = (float*)alloc((size_t)NN * 128 * 4);   // dinv-scaled h @ gcn_w
    int* cnt = (int*)alloc(NN * 4);
    int* cur = (int*)alloc(NN * 4);                     // adjacent to cnt (1 memset)
    int* offs = (int*)alloc((NN + 1) * 4);
    float* dinv = (float*)alloc(NN * 4);
    int* csr = (int*)alloc((size_t)EE * 4);
    float* score = (float*)alloc(NN * 4);
    unsigned* key = (unsigned*)alloc(NN * 4);
    int* rank = (int*)alloc(NN * 4);
    int* nidx = (int*)alloc(NN * 4);
    int* bcnt = (int*)alloc(65536 * 4);
    int* bcur = (int*)alloc(65536 * 4);                 // adjacent to bcnt (1 memset)
    int* boff = (int*)alloc((65536 + 1) * 4);
    int* bmem = (int*)alloc(NN * 4);
    double* part = (double*)alloc((size_t)BN2_NB * 128 * 2 * 8);
    float* scale1 = (float*)alloc(128 * 4);
    float* shift1 = (float*)alloc(128 * 4);
    float* scale2 = (float*)alloc(128 * 4);
    float* shift2 = (float*)alloc(128 * 4);
    int* bsum = (int*)alloc(128 * 4);

    float* out0 = (float*)d_out;                       // x_pool [K,128]
    float* out1 = out0 + (size_t)KTOP * 128;           // ei_new [2,E]
    float* out2 = out1 + (size_t)2 * EE;               // batch_new [K]

    int gemm_grid = (NN + 127) / 128;                  // 391

    // ---- graph prep (independent of feature path) ----
    hipMemsetAsync(cnt, 0, (size_t)((char*)cur - (char*)cnt) + NN * 4, stream);
    hipMemsetAsync(bcnt, 0, (size_t)((char*)bcur - (char*)bcnt) + 65536 * 4, stream);
    count_deg<<<(EE + 255) / 256, 256, 0, stream>>>(e_col, cnt, EE);
    {
        int B = (NN + 1023) / 1024;
        scan_phase1<<<B, 1024, 0, stream>>>(cnt, offs, bsum, dinv, NN);
        scan_phase2<<<1, 1024, 0, stream>>>(bsum, B, offs, NN);
        scan_phase3<<<B, 1024, 0, stream>>>(offs, bsum, NN);
    }
    fill_csr<<<(EE + 255) / 256, 256, 0, stream>>>(e_row, e_col, offs, cur, csr, EE);

    // ---- MLP: Linear (+ fused BN1 stats) ----
    gemm_bn_stats<<<gemm_grid, 256, 0, stream>>>(x, lin_w, lin_b, y, part, NN);
    bn_finalize<<<128, 256, 0, stream>>>(part, gemm_grid, bn1_g, bn1_b, scale1, shift1, NN);

    // ---- GCN: (BN1+ReLU fused) @ gcn_w, pre-scaled by dinv ----
    gemm_bn_apply<<<gemm_grid, 256, 0, stream>>>(y, gcn_w, scale1, shift1, dinv, hws, NN);
    gcn_agg<<<(NN + 3) / 4, 256, 0, stream>>>(hws, offs, csr, dinv, gcn_b, y, NN);

    // ---- BN2 stats ----
    bn_stats<<<BN2_NB, 128, 0, stream>>>(y, part, NN);
    bn_finalize<<<128, 256, 0, stream>>>(part, BN2_NB, bn2_g, bn2_b, scale2, shift2, NN);

    // ---- TopK pooling (BN2+ReLU fused into consumers) ----
    score_key<<<512, 256, 0, stream>>>(y, scale2, shift2, pool_w, score, key, bcnt, NN);
    {
        int B = 65536 / 1024;
        scan_phase1<<<B, 1024, 0, stream>>>(bcnt, boff, bsum, nullptr, 65536);
        scan_phase2<<<1, 1024, 0, stream>>>(bsum, B, boff, 65536);
        scan_phase3<<<B, 1024, 0, stream>>>(boff, bsum, 65536);
    }
    bucket_fill<<<(NN + 255) / 256, 256, 0, stream>>>(key, boff, bcur, bmem, NN);
    rank_kernel<<<(NN + 255) / 256, 256, 0, stream>>>(key, boff, bmem, rank, nidx, NN);

    // ---- outputs ----
    write_pool<<<(NN + 3) / 4, 128, 0, stream>>>(y, scale2, shift2, score, rank, out0, out2, NN);
    write_edges<<<(EE + 255) / 256, 256, 0, stream>>>(e_row, e_col, nidx, out1, EE);
}

// Round 11
// 361.932 us; speedup vs baseline: 2.4386x; 1.1149x over previous
//
#include <hip/hip_runtime.h>
#include <hip/hip_bf16.h>

#define NN 50000
#define EE 800000
#define KTOP 25000
#define EPSF 1e-5

// ---------------------------------------------------------------------------
// GEMM1: Y[M,128] = A[M,128] @ W[128,128] + bias, fused per-block BN partials.
// block 256 threads, tile 128x128, 8x8 micro-tile (B cols split tx*4 / 64+tx*4
// for conflict-free ds_read_b128). As padded [32][132]. 2 blocks/CU, ~110 VGPR
// (NOTE: (256,4)+chunked-W variant spilled 47MB to scratch — do not revisit).
// ---------------------------------------------------------------------------
__global__ __launch_bounds__(256, 2) void gemm_bn_stats(const float* __restrict__ A,
                                                        const float* __restrict__ W,
                                                        const float* __restrict__ bias,
                                                        float* __restrict__ Y,
                                                        double* __restrict__ part, int M) {
    __shared__ float Bs[128][128];   // 64 KiB: W, [k][n]
    __shared__ float As[32][132];    // padded: A-chunk transposed, [k][row]
    int t = threadIdx.x;
    int bm = blockIdx.x * 128;

    const float4* W4 = (const float4*)W;
    float4* Bs4 = (float4*)Bs;
#pragma unroll
    for (int i = 0; i < 16; i++) Bs4[t + i * 256] = W4[t + i * 256];

    float acc[8][8];
#pragma unroll
    for (int i = 0; i < 8; i++)
#pragma unroll
        for (int j = 0; j < 8; j++) acc[i][j] = 0.f;

    int ty = t >> 4;   // 0..15 row group (8 rows each)
    int tx = t & 15;   // 0..15 col group (cols tx*4..+4 and 64+tx*4..+4)

    for (int kc = 0; kc < 4; kc++) {
        __syncthreads();
#pragma unroll
        for (int i = 0; i < 4; i++) {
            int f4 = t + i * 256;
            int r = f4 >> 3, k4 = f4 & 7;
            int row = bm + r;
            float4 v = make_float4(0.f, 0.f, 0.f, 0.f);
            if (row < M) v = *(const float4*)&A[(size_t)row * 128 + kc * 32 + k4 * 4];
            As[k4 * 4 + 0][r] = v.x;
            As[k4 * 4 + 1][r] = v.y;
            As[k4 * 4 + 2][r] = v.z;
            As[k4 * 4 + 3][r] = v.w;
        }
        __syncthreads();
#pragma unroll
        for (int kk = 0; kk < 32; kk++) {
            float4 a0 = *(float4*)&As[kk][ty * 8];
            float4 a1 = *(float4*)&As[kk][ty * 8 + 4];
            float4 b0 = *(float4*)&Bs[kc * 32 + kk][tx * 4];
            float4 b1 = *(float4*)&Bs[kc * 32 + kk][64 + tx * 4];
            float av[8] = {a0.x, a0.y, a0.z, a0.w, a1.x, a1.y, a1.z, a1.w};
            float bv[8] = {b0.x, b0.y, b0.z, b0.w, b1.x, b1.y, b1.z, b1.w};
#pragma unroll
            for (int i = 0; i < 8; i++)
#pragma unroll
                for (int j = 0; j < 8; j++) acc[i][j] += av[i] * bv[j];
        }
    }

    float4 bb0 = *(const float4*)&bias[tx * 4];
    float4 bb1 = *(const float4*)&bias[64 + tx * 4];
    float s[8], s2[8];
#pragma unroll
    for (int j = 0; j < 8; j++) { s[j] = 0.f; s2[j] = 0.f; }
#pragma unroll
    for (int i = 0; i < 8; i++) {
        int row = bm + ty * 8 + i;
        if (row < M) {
            float4 y0, y1;
            y0.x = acc[i][0] + bb0.x; y0.y = acc[i][1] + bb0.y;
            y0.z = acc[i][2] + bb0.z; y0.w = acc[i][3] + bb0.w;
            y1.x = acc[i][4] + bb1.x; y1.y = acc[i][5] + bb1.y;
            y1.z = acc[i][6] + bb1.z; y1.w = acc[i][7] + bb1.w;
            *(float4*)&Y[(size_t)row * 128 + tx * 4] = y0;
            *(float4*)&Y[(size_t)row * 128 + 64 + tx * 4] = y1;
            s[0] += y0.x; s2[0] += y0.x * y0.x;
            s[1] += y0.y; s2[1] += y0.y * y0.y;
            s[2] += y0.z; s2[2] += y0.z * y0.z;
            s[3] += y0.w; s2[3] += y0.w * y0.w;
            s[4] += y1.x; s2[4] += y1.x * y1.x;
            s[5] += y1.y; s2[5] += y1.y * y1.y;
            s[6] += y1.z; s2[6] += y1.z * y1.z;
            s[7] += y1.w; s2[7] += y1.w * y1.w;
        }
    }
    __syncthreads();                       // As no longer needed
    float2* Sred = (float2*)As;            // [16][128] fits in padded As
#pragma unroll
    for (int j = 0; j < 8; j++) {
        int col = (j < 4) ? (tx * 4 + j) : (64 + tx * 4 + j - 4);
        Sred[ty * 128 + col] = make_float2(s[j], s2[j]);
    }
    __syncthreads();
    if (t < 128) {
        double S = 0.0, S2 = 0.0;
#pragma unroll
        for (int r = 0; r < 16; r++) {
            float2 v = Sred[r * 128 + t];
            S += (double)v.x;
            S2 += (double)v.y;
        }
        part[((size_t)blockIdx.x * 128 + t) * 2 + 0] = S;
        part[((size_t)blockIdx.x * 128 + t) * 2 + 1] = S2;
    }
}

// ---------------------------------------------------------------------------
// GEMM2: HWs[M,128] = dinv[row] * ( relu(bn1(Yin)) @ W ).  BN1 applied on the
// fly during A-staging; dinv scaling in epilogue. Same conflict-free layout.
// ---------------------------------------------------------------------------
__global__ __launch_bounds__(256, 2) void gemm_bn_apply(const float* __restrict__ Yin,
                                                        const float* __restrict__ W,
                                                        const float* __restrict__ sc,
                                                        const float* __restrict__ sh,
                                                        const float* __restrict__ dinv,
                                                        float* __restrict__ HWs, int M) {
    __shared__ float Bs[128][128];
    __shared__ float As[32][132];
    int t = threadIdx.x;
    int bm = blockIdx.x * 128;

    const float4* W4 = (const float4*)W;
    float4* Bs4 = (float4*)Bs;
#pragma unroll
    for (int i = 0; i < 16; i++) Bs4[t + i * 256] = W4[t + i * 256];

    float acc[8][8];
#pragma unroll
    for (int i = 0; i < 8; i++)
#pragma unroll
        for (int j = 0; j < 8; j++) acc[i][j] = 0.f;

    int ty = t >> 4;
    int tx = t & 15;

    for (int kc = 0; kc < 4; kc++) {
        __syncthreads();
#pragma unroll
        for (int i = 0; i < 4; i++) {
            int f4 = t + i * 256;
            int r = f4 >> 3, k4 = f4 & 7;
            int row = bm + r;
            int col = kc * 32 + k4 * 4;
            float4 v = make_float4(0.f, 0.f, 0.f, 0.f);
            if (row < M) {
                float4 y = *(const float4*)&Yin[(size_t)row * 128 + col];
                float4 scv = *(const float4*)&sc[col];
                float4 shv = *(const float4*)&sh[col];
                v.x = fmaxf(y.x * scv.x + shv.x, 0.f);
                v.y = fmaxf(y.y * scv.y + shv.y, 0.f);
                v.z = fmaxf(y.z * scv.z + shv.z, 0.f);
                v.w = fmaxf(y.w * scv.w + shv.w, 0.f);
            }
            As[k4 * 4 + 0][r] = v.x;
            As[k4 * 4 + 1][r] = v.y;
            As[k4 * 4 + 2][r] = v.z;
            As[k4 * 4 + 3][r] = v.w;
        }
        __syncthreads();
#pragma unroll
        for (int kk = 0; kk < 32; kk++) {
            float4 a0 = *(float4*)&As[kk][ty * 8];
            float4 a1 = *(float4*)&As[kk][ty * 8 + 4];
            float4 b0 = *(float4*)&Bs[kc * 32 + kk][tx * 4];
            float4 b1 = *(float4*)&Bs[kc * 32 + kk][64 + tx * 4];
            float av[8] = {a0.x, a0.y, a0.z, a0.w, a1.x, a1.y, a1.z, a1.w};
            float bv[8] = {b0.x, b0.y, b0.z, b0.w, b1.x, b1.y, b1.z, b1.w};
#pragma unroll
            for (int i = 0; i < 8; i++)
#pragma unroll
                for (int j = 0; j < 8; j++) acc[i][j] += av[i] * bv[j];
        }
    }
#pragma unroll
    for (int i = 0; i < 8; i++) {
        int row = bm + ty * 8 + i;
        if (row < M) {
            float di = dinv[row];
            float4 o0, o1;
            o0.x = acc[i][0] * di; o0.y = acc[i][1] * di;
            o0.z = acc[i][2] * di; o0.w = acc[i][3] * di;
            o1.x = acc[i][4] * di; o1.y = acc[i][5] * di;
            o1.z = acc[i][6] * di; o1.w = acc[i][7] * di;
            *(float4*)&HWs[(size_t)row * 128 + tx * 4] = o0;
            *(float4*)&HWs[(size_t)row * 128 + 64 + tx * 4] = o1;
        }
    }
}

// ---------------------------------------------------------------------------
// BN stats (for gcn output): 64 rows/block, unroll-4, f64 partials
// ---------------------------------------------------------------------------
#define BN2_ROWS 64
#define BN2_NB ((NN + BN2_ROWS - 1) / BN2_ROWS)   // 782

__global__ __launch_bounds__(128) void bn_stats(const float* __restrict__ Y,
                                                double* __restrict__ part, int M) {
    int c = threadIdx.x;
    int b = blockIdx.x;
    int r0 = b * BN2_ROWS;
    int r1 = min(M, r0 + BN2_ROWS);
    double s = 0.0, s2 = 0.0;
    int r = r0;
    for (; r + 4 <= r1; r += 4) {
        float v0 = Y[(size_t)r * 128 + c];
        float v1 = Y[(size_t)(r + 1) * 128 + c];
        float v2 = Y[(size_t)(r + 2) * 128 + c];
        float v3 = Y[(size_t)(r + 3) * 128 + c];
        s += (double)v0 + (double)v1 + (double)v2 + (double)v3;
        s2 += (double)v0 * v0 + (double)v1 * v1 + (double)v2 * v2 + (double)v3 * v3;
    }
    for (; r < r1; r++) {
        float v = Y[(size_t)r * 128 + c];
        s += (double)v;
        s2 += (double)v * v;
    }
    part[((size_t)b * 128 + c) * 2 + 0] = s;
    part[((size_t)b * 128 + c) * 2 + 1] = s2;
}

// ---------------------------------------------------------------------------
// BN finalize: parallel — one block per channel, 256 threads, LDS f64 tree.
// ---------------------------------------------------------------------------
__global__ __launch_bounds__(256) void bn_finalize(const double* __restrict__ part, int nb,
                                                   const float* __restrict__ g,
                                                   const float* __restrict__ beta,
                                                   float* __restrict__ scale,
                                                   float* __restrict__ shift, int M) {
    int c = blockIdx.x;
    int t = threadIdx.x;
    double s = 0.0, s2 = 0.0;
    for (int b = t; b < nb; b += 256) {
        s += part[((size_t)b * 128 + c) * 2 + 0];
        s2 += part[((size_t)b * 128 + c) * 2 + 1];
    }
    __shared__ double sd[256], sd2[256];
    sd[t] = s;
    sd2[t] = s2;
    __syncthreads();
#pragma unroll
    for (int o = 128; o > 0; o >>= 1) {
        if (t < o) {
            sd[t] += sd[t + o];
            sd2[t] += sd2[t + o];
        }
        __syncthreads();
    }
    if (t == 0) {
        double S = sd[0], S2 = sd2[0];
        double mu = S / (double)M;
        double var = S2 / (double)M - mu * mu;
        double inv = 1.0 / sqrt(var + (double)EPSF);
        scale[c] = (float)((double)g[c] * inv);
        shift[c] = (float)((double)beta[c] - mu * (double)g[c] * inv);
    }
}

// ---------------------------------------------------------------------------
// Graph: degree count, CSR build
// ---------------------------------------------------------------------------
__global__ __launch_bounds__(256) void count_deg(const int* __restrict__ col,
                                                 int* __restrict__ cnt, int E) {
    int e = blockIdx.x * 256 + threadIdx.x;
    if (e < E) atomicAdd(&cnt[col[e]], 1);
}

__global__ __launch_bounds__(256) void fill_csr(const int* __restrict__ row,
                                                const int* __restrict__ col,
                                                const int* __restrict__ off,
                                                int* __restrict__ cur,
                                                int* __restrict__ csr, int E) {
    int e = blockIdx.x * 256 + threadIdx.x;
    if (e < E) {
        int c = col[e];
        int p = atomicAdd(&cur[c], 1);
        csr[off[c] + p] = row[e];
    }
}

// ---------------------------------------------------------------------------
// Scan (3-phase exclusive scan; phase1 optionally emits dinv = rsqrt(cnt+1))
// ---------------------------------------------------------------------------
__device__ __forceinline__ int waveInclScan(int v, int lane) {
#pragma unroll
    for (int o = 1; o < 64; o <<= 1) {
        int u = __shfl_up(v, o, 64);
        if (lane >= o) v += u;
    }
    return v;
}

__global__ __launch_bounds__(1024) void scan_phase1(const int* __restrict__ in,
                                                    int* __restrict__ out,
                                                    int* __restrict__ bsum,
                                                    float* __restrict__ dinv, int n) {
    int t = threadIdx.x;
    int g = blockIdx.x * 1024 + t;
    int lane = t & 63, wid = t >> 6;
    int v = (g < n) ? in[g] : 0;
    if (dinv && g < n) dinv[g] = (float)(1.0 / sqrt((double)(v + 1)));
    int incl = waveInclScan(v, lane);
    __shared__ int ws[16];
    if (lane == 63) ws[wid] = incl;
    __syncthreads();
    if (t < 16) {
        int x = ws[t];
#pragma unroll
        for (int o = 1; o < 16; o <<= 1) {
            int u = __shfl_up(x, o, 64);
            if (t >= o) x += u;
        }
        ws[t] = x;
    }
    __syncthreads();
    int pre = (wid > 0) ? ws[wid - 1] : 0;
    if (g < n) out[g] = pre + incl - v;
    if (t == 1023) bsum[blockIdx.x] = ws[15];
}

__global__ __launch_bounds__(1024) void scan_phase2(int* __restrict__ bsum, int B,
                                                    int* __restrict__ out, int n) {
    int t = threadIdx.x;
    int lane = t & 63, wid = t >> 6;
    int v = (t < B) ? bsum[t] : 0;
    int incl = waveInclScan(v, lane);
    __shared__ int ws[16];
    if (lane == 63) ws[wid] = incl;
    __syncthreads();
    if (t < 16) {
        int x = ws[t];
#pragma unroll
        for (int o = 1; o < 16; o <<= 1) {
            int u = __shfl_up(x, o, 64);
            if (t >= o) x += u;
        }
        ws[t] = x;
    }
    __syncthreads();
    int pre = (wid > 0) ? ws[wid - 1] : 0;
    int glob_incl = pre + incl;
    if (t < B) bsum[t] = glob_incl - v;   // exclusive
    if (t == B - 1) out[n] = glob_incl;   // grand total
}

__global__ __launch_bounds__(1024) void scan_phase3(int* __restrict__ out,
                                                    const int* __restrict__ bsum, int n) {
    int g = blockIdx.x * 1024 + threadIdx.x;
    if (g < n) out[g] += bsum[blockIdx.x];
}

// ---------------------------------------------------------------------------
// GCN aggregation: one WAVE per node (4 nodes / 256-thr block), float2 per
// lane, unroll-8 gathers for MLP. HWs is pre-scaled by dinv[src].
// OUT[i] = dinv[i]*( sum_src HWs[src] + HWs[i] ) + gcn_b
// ---------------------------------------------------------------------------
__global__ __launch_bounds__(256) void gcn_agg(const float* __restrict__ HWs,
                                               const int* __restrict__ off,
                                               const int* __restrict__ csr,
                                               const float* __restrict__ dinv,
                                               const float* __restrict__ gcn_b,
                                               float* __restrict__ OUT, int M) {
    int lane = threadIdx.x & 63;
    int i = blockIdx.x * 4 + (threadIdx.x >> 6);
    if (i >= M) return;
    const float2* H2 = (const float2*)HWs;
    int o0 = off[i], o1 = off[i + 1];
    float2 hv = H2[(size_t)i * 64 + lane];   // self loop term
    double ax = (double)hv.x, ay = (double)hv.y;
    int e = o0;
    for (; e + 8 <= o1; e += 8) {
        int s0 = csr[e], s1 = csr[e + 1], s2 = csr[e + 2], s3 = csr[e + 3];
        int s4 = csr[e + 4], s5 = csr[e + 5], s6 = csr[e + 6], s7 = csr[e + 7];
        float2 v0 = H2[(size_t)s0 * 64 + lane];
        float2 v1 = H2[(size_t)s1 * 64 + lane];
        float2 v2 = H2[(size_t)s2 * 64 + lane];
        float2 v3 = H2[(size_t)s3 * 64 + lane];
        float2 v4 = H2[(size_t)s4 * 64 + lane];
        float2 v5 = H2[(size_t)s5 * 64 + lane];
        float2 v6 = H2[(size_t)s6 * 64 + lane];
        float2 v7 = H2[(size_t)s7 * 64 + lane];
        ax += ((double)v0.x + (double)v1.x) + ((double)v2.x + (double)v3.x) +
              ((double)v4.x + (double)v5.x) + ((double)v6.x + (double)v7.x);
        ay += ((double)v0.y + (double)v1.y) + ((double)v2.y + (double)v3.y) +
              ((double)v4.y + (double)v5.y) + ((double)v6.y + (double)v7.y);
    }
    for (; e < o1; e++) {
        float2 v = H2[(size_t)csr[e] * 64 + lane];
        ax += (double)v.x;
        ay += (double)v.y;
    }
    double di = (double)dinv[i];
    float2 ob = ((const float2*)gcn_b)[lane];
    float2 o;
    o.x = (float)(ax * di) + ob.x;
    o.y = (float)(ay * di) + ob.y;
    ((float2*)OUT)[(size_t)i * 64 + lane] = o;
}

// ---------------------------------------------------------------------------
// Score (BN2+ReLU on the fly) + orderable key (raw pre-tanh v) + histogram.
// tanh is monotone so ranking on v is identical; v's exponent spread avoids
// tanh-saturation bucket blowup.
// ---------------------------------------------------------------------------
__global__ __launch_bounds__(256) void score_key(const float* __restrict__ Y2,
                                                 const float* __restrict__ sc,
                                                 const float* __restrict__ sh,
                                                 const float* __restrict__ w,
                                                 float* __restrict__ score,
                                                 unsigned* __restrict__ key,
                                                 int* __restrict__ bcnt, int M) {
    int lane = threadIdx.x & 63;
    int wid = threadIdx.x >> 6;
    int gw = blockIdx.x * 4 + wid;
    int nw = gridDim.x * 4;

    float w0 = w[lane], w1 = w[lane + 64];
    float sc0 = sc[lane], sh0 = sh[lane];
    float sc1 = sc[lane + 64], sh1 = sh[lane + 64];

    float nv = w0 * w0 + w1 * w1;
#pragma unroll
    for (int o = 32; o >= 1; o >>= 1) nv += __shfl_xor(nv, o, 64);
    float nrm = sqrtf(nv);

    for (int r = gw; r < M; r += nw) {
        float a = Y2[(size_t)r * 128 + lane];
        float b = Y2[(size_t)r * 128 + lane + 64];
        a = fmaxf(a * sc0 + sh0, 0.f);
        b = fmaxf(b * sc1 + sh1, 0.f);
        float v = a * w0 + b * w1;
#pragma unroll
        for (int o = 32; o >= 1; o >>= 1) v += __shfl_xor(v, o, 64);
        if (lane == 0) {
            score[r] = tanhf(v / nrm);
            unsigned u = __float_as_uint(v);
            unsigned k = (u & 0x80000000u) ? ~u : (u | 0x80000000u);
            key[r] = k;
            atomicAdd(&bcnt[k >> 16], 1);
        }
    }
}

__global__ __launch_bounds__(256) void bucket_fill(const unsigned* __restrict__ key,
                                                   const int* __restrict__ boff,
                                                   int* __restrict__ bcur,
                                                   int* __restrict__ bmem, int M) {
    int i = blockIdx.x * 256 + threadIdx.x;
    if (i < M) {
        int b = key[i] >> 16;
        int p = atomicAdd(&bcur[b], 1);
        bmem[boff[b] + p] = i;
    }
}

__global__ __launch_bounds__(256) void rank_kernel(const unsigned* __restrict__ key,
                                                   const int* __restrict__ boff,
                                                   const int* __restrict__ bmem,
                                                   int* __restrict__ rank,
                                                   int* __restrict__ nidx, int M) {
    int i = blockIdx.x * 256 + threadIdx.x;
    if (i >= M) return;
    unsigned ki = key[i];
    int b = ki >> 16;
    int r = M - boff[b + 1];   // all keys in strictly-greater buckets
    int p0 = boff[b], p1 = boff[b + 1];
    for (int p = p0; p < p1; p++) {
        int j = bmem[p];
        unsigned kj = key[j];
        if (kj > ki || (kj == ki && j < i)) r++;
    }
    rank[i] = r;
    nidx[i] = (r < KTOP) ? r : -1;
}

// ---------------------------------------------------------------------------
// Output writers (d_out: [x_pool K*128 | ei_new 2E | batch_new K], all f32)
// write_pool: 4 nodes per 128-thr block, float4 per thread (32 thr/node)
// ---------------------------------------------------------------------------
__global__ __launch_bounds__(128) void write_pool(const float* __restrict__ Y2,
                                                  const float* __restrict__ sc,
                                                  const float* __restrict__ sh,
                                                  const float* __restrict__ score,
                                                  const int* __restrict__ rank,
                                                  float* __restrict__ out0,
                                                  float* __restrict__ out2, int M) {
    int sub = threadIdx.x >> 5;              // 0..3 node within block
    int c4 = threadIdx.x & 31;               // float4 index 0..31
    int i = blockIdx.x * 4 + sub;
    if (i >= M) return;
    int r = rank[i];
    if (r < KTOP) {
        float s = score[i];
        float4 y = *(const float4*)&Y2[(size_t)i * 128 + c4 * 4];
        float4 scv = *(const float4*)&sc[c4 * 4];
        float4 shv = *(const float4*)&sh[c4 * 4];
        float4 o;
        o.x = fmaxf(y.x * scv.x + shv.x, 0.f) * s;
        o.y = fmaxf(y.y * scv.y + shv.y, 0.f) * s;
        o.z = fmaxf(y.z * scv.z + shv.z, 0.f) * s;
        o.w = fmaxf(y.w * scv.w + shv.w, 0.f) * s;
        *(float4*)&out0[(size_t)r * 128 + c4 * 4] = o;
        if (c4 == 0) out2[r] = 0.0f;   // batch_new (batch is all zeros)
    }
}

__global__ __launch_bounds__(256) void write_edges(const int* __restrict__ row,
                                                   const int* __restrict__ col,
                                                   const int* __restrict__ nidx,
                                                   float* __restrict__ out1, int E) {
    int e = blockIdx.x * 256 + threadIdx.x;
    if (e < E) {
        int a = nidx[row[e]];
        int b = nidx[col[e]];
        bool keep = (a >= 0) && (b >= 0);
        out1[e] = keep ? (float)a : -1.0f;
        out1[E + e] = keep ? (float)b : -1.0f;
    }
}

// ---------------------------------------------------------------------------
extern "C" void kernel_launch(void* const* d_in, const int* in_sizes, int n_in,
                              void* d_out, int out_size, void* d_ws, size_t ws_size,
                              hipStream_t stream) {
    const float* x = (const float*)d_in[0];
    const int* ei = (const int*)d_in[1];
    const float* lin_w = (const float*)d_in[3];
    const float* lin_b = (const float*)d_in[4];
    const float* bn1_g = (const float*)d_in[5];
    const float* bn1_b = (const float*)d_in[6];
    const float* gcn_w = (const float*)d_in[7];
    const float* gcn_b = (const float*)d_in[8];
    const float* bn2_g = (const float*)d_in[9];
    const float* bn2_b = (const float*)d_in[10];
    const float* pool_w = (const float*)d_in[11];

    const int* e_row = ei;        // edge_index[0]
    const int* e_col = ei + EE;   // edge_index[1]

    char* ws = (char*)d_ws;
    size_t off_b = 0;
    auto alloc = [&](size_t bytes) -> void* {
        void* p = ws + off_b;
        off_b = (off_b + bytes + 255) & ~(size_t)255;
        return p;
    };
    float* y = (float*)alloc((size_t)NN * 128 * 4);     // gemm1 out, later gcn out (y2)
    float* hws = (float*)alloc((size_t)NN * 128 * 4);   // dinv-scaled h @ gcn_w
    int* cnt = (int*)alloc(NN * 4);
    int* cur = (int*)alloc(NN * 4);                     // adjacent to cnt (1 memset)
    int* offs = (int*)alloc((NN + 1) * 4);
    float* dinv = (float*)alloc(NN * 4);
    int* csr = (int*)alloc((size_t)EE * 4);
    float* score = (float*)alloc(NN * 4);
    unsigned* key = (unsigned*)alloc(NN * 4);
    int* rank = (int*)alloc(NN * 4);
    int* nidx = (int*)alloc(NN * 4);
    int* bcnt = (int*)alloc(65536 * 4);
    int* bcur = (int*)alloc(65536 * 4);                 // adjacent to bcnt (1 memset)
    int* boff = (int*)alloc((65536 + 1) * 4);
    int* bmem = (int*)alloc(NN * 4);
    double* part = (double*)alloc((size_t)BN2_NB * 128 * 2 * 8);
    float* scale1 = (float*)alloc(128 * 4);
    float* shift1 = (float*)alloc(128 * 4);
    float* scale2 = (float*)alloc(128 * 4);
    float* shift2 = (float*)alloc(128 * 4);
    int* bsum = (int*)alloc(128 * 4);

    float* out0 = (float*)d_out;                       // x_pool [K,128]
    float* out1 = out0 + (size_t)KTOP * 128;           // ei_new [2,E]
    float* out2 = out1 + (size_t)2 * EE;               // batch_new [K]

    int gemm_grid = (NN + 127) / 128;                  // 391

    // ---- graph prep (independent of feature path) ----
    hipMemsetAsync(cnt, 0, (size_t)((char*)cur - (char*)cnt) + NN * 4, stream);
    hipMemsetAsync(bcnt, 0, (size_t)((char*)bcur - (char*)bcnt) + 65536 * 4, stream);
    count_deg<<<(EE + 255) / 256, 256, 0, stream>>>(e_col, cnt, EE);
    {
        int B = (NN + 1023) / 1024;
        scan_phase1<<<B, 1024, 0, stream>>>(cnt, offs, bsum, dinv, NN);
        scan_phase2<<<1, 1024, 0, stream>>>(bsum, B, offs, NN);
        scan_phase3<<<B, 1024, 0, stream>>>(offs, bsum, NN);
    }
    fill_csr<<<(EE + 255) / 256, 256, 0, stream>>>(e_row, e_col, offs, cur, csr, EE);

    // ---- MLP: Linear (+ fused BN1 stats) ----
    gemm_bn_stats<<<gemm_grid, 256, 0, stream>>>(x, lin_w, lin_b, y, part, NN);
    bn_finalize<<<128, 256, 0, stream>>>(part, gemm_grid, bn1_g, bn1_b, scale1, shift1, NN);

    // ---- GCN: (BN1+ReLU fused) @ gcn_w, pre-scaled by dinv ----
    gemm_bn_apply<<<gemm_grid, 256, 0, stream>>>(y, gcn_w, scale1, shift1, dinv, hws, NN);
    gcn_agg<<<(NN + 3) / 4, 256, 0, stream>>>(hws, offs, csr, dinv, gcn_b, y, NN);

    // ---- BN2 stats ----
    bn_stats<<<BN2_NB, 128, 0, stream>>>(y, part, NN);
    bn_finalize<<<128, 256, 0, stream>>>(part, BN2_NB, bn2_g, bn2_b, scale2, shift2, NN);

    // ---- TopK pooling (BN2+ReLU fused into consumers) ----
    score_key<<<512, 256, 0, stream>>>(y, scale2, shift2, pool_w, score, key, bcnt, NN);
    {
        int B = 65536 / 1024;
        scan_phase1<<<B, 1024, 0, stream>>>(bcnt, boff, bsum, nullptr, 65536);
        scan_phase2<<<1, 1024, 0, stream>>>(bsum, B, boff, 65536);
        scan_phase3<<<B, 1024, 0, stream>>>(boff, bsum, 65536);
    }
    bucket_fill<<<(NN + 255) / 256, 256, 0, stream>>>(key, boff, bcur, bmem, NN);
    rank_kernel<<<(NN + 255) / 256, 256, 0, stream>>>(key, boff, bmem, rank, nidx, NN);

    // ---- outputs ----
    write_pool<<<(NN + 3) / 4, 128, 0, stream>>>(y, scale2, shift2, score, rank, out0, out2, NN);
    write_edges<<<(EE + 255) / 256, 256, 0, stream>>>(e_row, e_col, nidx, out1, EE);
}